// Round 4
// baseline (182.710 us; speedup 1.0000x reference)
//
#include <hip/hip_runtime.h>

#define HH 56
#define WW 56
#define HWSZ 3136
#define KS 7
#define KK 49

typedef __attribute__((ext_vector_type(8))) short short8;
typedef __attribute__((ext_vector_type(4))) float f32x4;

__device__ inline unsigned short f2bf(float f) {
    unsigned u = __builtin_bit_cast(unsigned, f);
    u += 0x7FFF + ((u >> 16) & 1);          // RNE
    return (unsigned short)(u >> 16);
}
__device__ inline float bflo(unsigned u) { return __builtin_bit_cast(float, u << 16); }
__device__ inline float bfhi(unsigned u) { return __builtin_bit_cast(float, u & 0xFFFF0000u); }

// --------- Kernel A (MFMA): t[p][64] = relu(BN(x @ w1^T)) in bf16 ---------
// grid 197: blocks 0..195 = 64-pixel tiles; block 196 = w2->bf16 prep.
// LDS holds x-tile transposed bf16 [cblk][64p][8c] and w1 bf16 [cblk][64o][8c].
__global__ __launch_bounds__(256) void ka_mfma(
    const float* __restrict__ x, const float* __restrict__ w1,
    const float* __restrict__ gamma, const float* __restrict__ beta,
    const float* __restrict__ mean, const float* __restrict__ var,
    const float* __restrict__ w2,
    unsigned short* __restrict__ t_bf, unsigned short* __restrict__ w2p)
{
    const int tid = threadIdx.x;
    if (blockIdx.x == 196) {
        for (int gi = 0; gi < 16; ++gi)
            for (int i = tid; i < 64 * 64; i += 256) {
                int r = i >> 6, k = i & 63;
                float v = (r < KK) ? w2[(gi * KK + r) * 64 + k] : 0.f;
                w2p[(size_t)(gi * 64 + r) * 64 + k] = f2bf(v);
            }
        return;
    }

    __shared__ __align__(16) unsigned short xls[32 * 64 * 8];  // 32 KB
    __shared__ __align__(16) unsigned short wls[32 * 64 * 8];  // 32 KB

    const int p0 = blockIdx.x * 64;
    const int b = p0 / HWSZ, hw0 = p0 - b * HWSZ;

    // ---- stage x tile: [c][p] -> bf16 LDS [cblk][p][8c], coalesced reads ----
    {
        const int pl = tid & 63, cb0 = tid >> 6;
        const float* xb = x + (size_t)b * 256 * HWSZ + hw0 + pl;
        #pragma unroll
        for (int ps = 0; ps < 8; ++ps) {
            const int cb = ps * 4 + cb0;
            const int c0 = cb * 8;
            unsigned u[4];
            #pragma unroll
            for (int j = 0; j < 4; ++j) {
                float va = xb[(size_t)(c0 + 2 * j) * HWSZ];
                float vb = xb[(size_t)(c0 + 2 * j + 1) * HWSZ];
                u[j] = (unsigned)f2bf(va) | ((unsigned)f2bf(vb) << 16);
            }
            *(uint4*)&xls[cb * 512 + pl * 8] = make_uint4(u[0], u[1], u[2], u[3]);
        }
    }
    // ---- stage w1: [o][c] -> bf16 LDS [cblk][o][8c] (per-lane row reads) ----
    {
        const int o = tid & 63, cb0 = tid >> 6;
        #pragma unroll
        for (int ps = 0; ps < 8; ++ps) {
            const int cb = ps * 4 + cb0;
            const float* wr = w1 + o * 256 + cb * 8;
            float4 f0 = *(const float4*)wr;
            float4 f1 = *(const float4*)(wr + 4);
            unsigned u0 = (unsigned)f2bf(f0.x) | ((unsigned)f2bf(f0.y) << 16);
            unsigned u1 = (unsigned)f2bf(f0.z) | ((unsigned)f2bf(f0.w) << 16);
            unsigned u2 = (unsigned)f2bf(f1.x) | ((unsigned)f2bf(f1.y) << 16);
            unsigned u3 = (unsigned)f2bf(f1.z) | ((unsigned)f2bf(f1.w) << 16);
            *(uint4*)&wls[cb * 512 + o * 8] = make_uint4(u0, u1, u2, u3);
        }
    }
    __syncthreads();

    // ---- MFMA: wave wv owns o-tile wv; D[o][p] = sum_c w1[o,c] x[p,c] ----
    const int lane = tid & 63, wv = tid >> 6;
    const int m = lane & 15, q = lane >> 4;

    short8 af[8];
    #pragma unroll
    for (int ks = 0; ks < 8; ++ks)
        af[ks] = *(const short8*)&wls[(ks * 4 + q) * 512 + (wv * 16 + m) * 8];

    #pragma unroll
    for (int nt = 0; nt < 4; ++nt) {
        f32x4 acc = {0.f, 0.f, 0.f, 0.f};
        #pragma unroll
        for (int ks = 0; ks < 8; ++ks) {
            short8 bfr = *(const short8*)&xls[(ks * 4 + q) * 512 + (nt * 16 + m) * 8];
            acc = __builtin_amdgcn_mfma_f32_16x16x32_bf16(af[ks], bfr, acc, 0, 0, 0);
        }
        // D: col(lane&15)=p, row((lane>>4)*4+j)=o
        const int ob = wv * 16 + q * 4;
        float4 g4 = *(const float4*)&gamma[ob];
        float4 v4 = *(const float4*)&var[ob];
        float4 m4 = *(const float4*)&mean[ob];
        float4 b4 = *(const float4*)&beta[ob];
        float gg[4] = {g4.x, g4.y, g4.z, g4.w};
        float vv[4] = {v4.x, v4.y, v4.z, v4.w};
        float mm[4] = {m4.x, m4.y, m4.z, m4.w};
        float bb[4] = {b4.x, b4.y, b4.z, b4.w};
        unsigned r0 = 0, r1 = 0;
        #pragma unroll
        for (int j = 0; j < 4; ++j) {
            float sc = gg[j] * rsqrtf(vv[j] + 1e-5f);
            float sh = bb[j] - mm[j] * sc;
            float val = acc[j] * sc + sh;
            val = val > 0.f ? val : 0.f;
            unsigned hb = f2bf(val);
            if (j < 2) r0 |= hb << (16 * j);
            else       r1 |= hb << (16 * (j - 2));
        }
        const int p = p0 + nt * 16 + m;
        *(uint2*)&t_bf[(size_t)p * 64 + ob] = make_uint2(r0, r1);
    }
}

// --------- Kernel B: MFMA weight-GEMM (2 groups) + reg-resident dynamic conv ---------
// grid 1792 = 8 group-pairs x 224 (b,h); block 256 (4 waves)
__global__ __launch_bounds__(256, 4) void kb_fused(
    const float* __restrict__ y, const float* __restrict__ b2,
    const unsigned short* __restrict__ t_bf, const unsigned short* __restrict__ w2p,
    float* __restrict__ out)
{
    // wgt bf16 [2 groups][52 kk][68 px-stride]  (rows 8B-aligned: 136 B)
    __shared__ __align__(16) unsigned short wgt[2 * 52 * 68];

    const int tid = threadIdx.x;
    const int gp = blockIdx.x & 7;
    const int bh = blockIdx.x >> 3;            // 0..223
    const int b = bh / HH, h = bh - b * HH;

    // ---- phase 1: MFMA  wgt[g][kk][px] = sum_k t[px][k] * w2p[g][kk][k] + b2 ----
    {
        const int lane = tid & 63, wv = tid >> 6;
        const int m = lane & 15, q = lane >> 4;
        #pragma unroll
        for (int it = 0; it < 2; ++it) {
            const int tsk = wv + 4 * it;       // 0..7 = 2 groups x 4 pixel-tiles
            const int gl = tsk >> 2, pt = tsk & 3;
            const int g = gp * 2 + gl;
            const int prow = b * HWSZ + h * WW + pt * 16 + m;
            const short8* ta = (const short8*)(t_bf + (size_t)prow * 64 + q * 8);
            short8 a0 = ta[0];                 // k = q*8 + 0..7
            short8 a1 = ta[4];                 // k = 32 + q*8 + 0..7
            f32x4 acc[4];
            #pragma unroll
            for (int mt = 0; mt < 4; ++mt) { acc[mt][0]=0.f; acc[mt][1]=0.f; acc[mt][2]=0.f; acc[mt][3]=0.f; }
            #pragma unroll
            for (int mt = 0; mt < 4; ++mt) {
                const short8* tb = (const short8*)(w2p +
                    (size_t)(g * 64 + mt * 16 + m) * 64 + q * 8);
                short8 b0 = tb[0], b1 = tb[4];
                acc[mt] = __builtin_amdgcn_mfma_f32_16x16x32_bf16(a0, b0, acc[mt], 0, 0, 0);
                acc[mt] = __builtin_amdgcn_mfma_f32_16x16x32_bf16(a1, b1, acc[mt], 0, 0, 0);
            }
            // D: col(kk)=lane&15, row(px)=(lane>>4)*4+j
            #pragma unroll
            for (int mt = 0; mt < 4; ++mt) {
                const int kk = mt * 16 + m;
                if (kk < 52) {
                    float bv = (kk < KK) ? b2[g * KK + kk] : 0.f;
                    f32x4 v = acc[mt];
                    unsigned r0 = (unsigned)f2bf(v[0] + bv) | ((unsigned)f2bf(v[1] + bv) << 16);
                    unsigned r1 = (unsigned)f2bf(v[2] + bv) | ((unsigned)f2bf(v[3] + bv) << 16);
                    const int pxb = pt * 16 + q * 4;
                    *(uint2*)&wgt[(gl * 52 + kk) * 68 + pxb] = make_uint2(r0, r1);
                }
            }
        }
    }
    __syncthreads();

    // ---- phase 2: conv; per cc: batch-load all 21 y-quads, then FMA ----
    if (tid < 224) {
        const int gl = tid / 112;
        const int rem = tid - gl * 112;
        const int c2 = rem / 14, pq = rem - c2 * 14;
        const int g = gp * 2 + gl;
        const int cc0 = c2 * 2;
        const unsigned short* wg = &wgt[gl * 52 * 68 + pq * 4];
        const float4 z4 = make_float4(0.f, 0.f, 0.f, 0.f);
        const bool eL = (pq > 0), eR = (pq < 13);

        float* o0 = out + (size_t)(b * 256 + g * 16 + cc0) * HWSZ + h * WW + pq * 4;

        #pragma unroll
        for (int ci = 0; ci < 2; ++ci) {
            const float* yb = y + (size_t)(b * 256 + g * 16 + cc0 + ci) * HWSZ;
            // batch-load all 7 rows x 3 quads (invalid -> 0)
            float4 qv[7][3];
            #pragma unroll
            for (int di = 0; di < KS; ++di) {
                const int hs = h - 3 + di;
                const bool rv = (hs >= 0) && (hs < HH);
                const float* yr = yb + hs * WW + pq * 4 - 4;
                qv[di][0] = (rv && eL) ? *(const float4*)yr       : z4;
                qv[di][1] = rv         ? *(const float4*)(yr + 4) : z4;
                qv[di][2] = (rv && eR) ? *(const float4*)(yr + 8) : z4;
            }
            float a0 = 0.f, a1 = 0.f, a2 = 0.f, a3 = 0.f;
            #pragma unroll
            for (int di = 0; di < KS; ++di) {
                float w0[12] = {qv[di][0].x, qv[di][0].y, qv[di][0].z, qv[di][0].w,
                                qv[di][1].x, qv[di][1].y, qv[di][1].z, qv[di][1].w,
                                qv[di][2].x, qv[di][2].y, qv[di][2].z, qv[di][2].w};
                #pragma unroll
                for (int dj = 0; dj < KS; ++dj) {
                    uint2 wr = *(const uint2*)&wg[(di * KS + dj) * 68];
                    a0 += bflo(wr.x) * w0[dj + 1];
                    a1 += bfhi(wr.x) * w0[dj + 2];
                    a2 += bflo(wr.y) * w0[dj + 3];
                    a3 += bfhi(wr.y) * w0[dj + 4];
                }
            }
            *(float4*)(o0 + (size_t)ci * HWSZ) = make_float4(a0, a1, a2, a3);
        }
    }
}

extern "C" void kernel_launch(void* const* d_in, const int* in_sizes, int n_in,
                              void* d_out, int out_size, void* d_ws, size_t ws_size,
                              hipStream_t stream) {
    const float* x     = (const float*)d_in[0];
    const float* y     = (const float*)d_in[1];
    const float* w1    = (const float*)d_in[2];
    const float* gamma = (const float*)d_in[3];
    const float* beta  = (const float*)d_in[4];
    const float* mean  = (const float*)d_in[5];
    const float* var   = (const float*)d_in[6];
    const float* w2    = (const float*)d_in[7];
    const float* b2    = (const float*)d_in[8];
    float* out = (float*)d_out;

    unsigned short* t_bf = (unsigned short*)d_ws;          // [12608][64] bf16
    unsigned short* w2p  = t_bf + (size_t)12608 * 64;      // [16*64][64] bf16

    ka_mfma<<<197, 256, 0, stream>>>(x, w1, gamma, beta, mean, var, w2, t_bf, w2p);
    kb_fused<<<1792, 256, 0, stream>>>(y, b2, t_bf, w2p, out);
}

// Round 5
// 108.240 us; speedup vs baseline: 1.6880x; 1.6880x over previous
//
#include <hip/hip_runtime.h>

#define HH 56
#define WW 56
#define HWSZ 3136
#define KS 7
#define KK 49

typedef __attribute__((ext_vector_type(8))) short short8;
typedef __attribute__((ext_vector_type(4))) float f32x4;

__device__ inline unsigned short f2bf(float f) {
    unsigned u = __builtin_bit_cast(unsigned, f);
    u += 0x7FFF + ((u >> 16) & 1);          // RNE
    return (unsigned short)(u >> 16);
}
__device__ inline float bflo(unsigned u) { return __builtin_bit_cast(float, u << 16); }
__device__ inline float bfhi(unsigned u) { return __builtin_bit_cast(float, u & 0xFFFF0000u); }

// --------- Kernel A (MFMA): t[p][64] = relu(BN(x @ w1^T)) in bf16 ---------
// grid 393: blocks 0..391 = 32-pixel tiles; block 392 = w2->bf16 prep.
#define XSTR 260   // shorts per c-block row: 32px*8c + 4 pad
__global__ __launch_bounds__(256) void ka_mfma(
    const float* __restrict__ x, const float* __restrict__ w1,
    const float* __restrict__ gamma, const float* __restrict__ beta,
    const float* __restrict__ mean, const float* __restrict__ var,
    const float* __restrict__ w2,
    unsigned short* __restrict__ t_bf, unsigned short* __restrict__ w2p)
{
    const int tid = threadIdx.x;
    if (blockIdx.x == 392) {
        for (int gi = 0; gi < 16; ++gi)
            for (int i = tid; i < 64 * 64; i += 256) {
                int r = i >> 6, k = i & 63;
                float v = (r < KK) ? w2[(gi * KK + r) * 64 + k] : 0.f;
                w2p[(size_t)(gi * 64 + r) * 64 + k] = f2bf(v);
            }
        return;
    }

    __shared__ __align__(16) unsigned short xls[32 * XSTR];   // ~16.6 KB

    const int p0 = blockIdx.x * 32;
    const int b = p0 / HWSZ, hw0 = p0 - b * HWSZ;

    // ---- stage x tile: [c][p] -> bf16 LDS [cblk][32p][8c] ----
    {
        const int pl = tid & 31, cb0 = tid >> 5;   // cb0 0..7
        const float* xb = x + (size_t)b * 256 * HWSZ + hw0 + pl;
        #pragma unroll
        for (int ps = 0; ps < 4; ++ps) {
            const int cb = ps * 8 + cb0;
            const int c0 = cb * 8;
            unsigned u[4];
            #pragma unroll
            for (int j = 0; j < 4; ++j) {
                float va = xb[(size_t)(c0 + 2 * j) * HWSZ];
                float vb = xb[(size_t)(c0 + 2 * j + 1) * HWSZ];
                u[j] = (unsigned)f2bf(va) | ((unsigned)f2bf(vb) << 16);
            }
            *(uint4*)&xls[cb * XSTR + pl * 8] = make_uint4(u[0], u[1], u[2], u[3]);
        }
    }

    const int lane = tid & 63, wv = tid >> 6;
    const int m = lane & 15, q = lane >> 4;

    // ---- A-fragments straight from global w1 (L2-hot): o=wv*16+m, c=ks*32+q*8+j ----
    short8 af[8];
    {
        const float* wrow = w1 + (wv * 16 + m) * 256 + q * 8;
        #pragma unroll
        for (int ks = 0; ks < 8; ++ks) {
            float4 f0 = *(const float4*)(wrow + ks * 32);
            float4 f1 = *(const float4*)(wrow + ks * 32 + 4);
            short8 s;
            s[0] = (short)f2bf(f0.x); s[1] = (short)f2bf(f0.y);
            s[2] = (short)f2bf(f0.z); s[3] = (short)f2bf(f0.w);
            s[4] = (short)f2bf(f1.x); s[5] = (short)f2bf(f1.y);
            s[6] = (short)f2bf(f1.z); s[7] = (short)f2bf(f1.w);
            af[ks] = s;
        }
    }
    __syncthreads();

    // ---- MFMA: D[o][p], 2 pixel-subtiles ----
    #pragma unroll
    for (int nt = 0; nt < 2; ++nt) {
        f32x4 acc = {0.f, 0.f, 0.f, 0.f};
        #pragma unroll
        for (int ks = 0; ks < 8; ++ks) {
            short8 bfr = *(const short8*)&xls[(ks * 4 + q) * XSTR + (nt * 16 + m) * 8];
            acc = __builtin_amdgcn_mfma_f32_16x16x32_bf16(af[ks], bfr, acc, 0, 0, 0);
        }
        // D: col(lane&15)=p, row((lane>>4)*4+j)=o
        const int ob = wv * 16 + q * 4;
        float4 g4 = *(const float4*)&gamma[ob];
        float4 v4 = *(const float4*)&var[ob];
        float4 m4 = *(const float4*)&mean[ob];
        float4 b4 = *(const float4*)&beta[ob];
        float gg[4] = {g4.x, g4.y, g4.z, g4.w};
        float vv[4] = {v4.x, v4.y, v4.z, v4.w};
        float mm[4] = {m4.x, m4.y, m4.z, m4.w};
        float bb[4] = {b4.x, b4.y, b4.z, b4.w};
        unsigned r0 = 0, r1 = 0;
        #pragma unroll
        for (int j = 0; j < 4; ++j) {
            float sc = gg[j] * rsqrtf(vv[j] + 1e-5f);
            float sh = bb[j] - mm[j] * sc;
            float val = acc[j] * sc + sh;
            val = val > 0.f ? val : 0.f;
            unsigned hb = f2bf(val);
            if (j < 2) r0 |= hb << (16 * j);
            else       r1 |= hb << (16 * (j - 2));
        }
        const int p = p0 + nt * 16 + m;
        *(uint2*)&t_bf[(size_t)p * 64 + ob] = make_uint2(r0, r1);
    }
}

// --------- Kernel B: MFMA weight-GEMM (2 groups) + pipelined dynamic conv ---------
// grid 1792 = 8 group-pairs x 224 (b,h); block 256 (4 waves)
__global__ __launch_bounds__(256) void kb_fused(
    const float* __restrict__ y, const float* __restrict__ b2,
    const unsigned short* __restrict__ t_bf, const unsigned short* __restrict__ w2p,
    float* __restrict__ out)
{
    // wgt bf16 [2 groups][52 kk][68 px-stride]
    __shared__ __align__(16) unsigned short wgt[2 * 52 * 68];

    const int tid = threadIdx.x;
    const int gp = blockIdx.x & 7;             // XCD swizzle
    const int bh = blockIdx.x >> 3;            // 0..223
    const int b = bh / HH, h = bh - b * HH;

    // ---- phase 1: MFMA  wgt[g][kk][px] = sum_k t[px][k] * w2p[g][kk][k] + b2 ----
    {
        const int lane = tid & 63, wv = tid >> 6;
        const int m = lane & 15, q = lane >> 4;
        #pragma unroll
        for (int it = 0; it < 2; ++it) {
            const int tsk = wv + 4 * it;       // 0..7 = 2 groups x 4 pixel-tiles
            const int gl = tsk >> 2, pt = tsk & 3;
            const int g = gp * 2 + gl;
            const int prow = b * HWSZ + h * WW + pt * 16 + m;
            const short8* ta = (const short8*)(t_bf + (size_t)prow * 64 + q * 8);
            short8 a0 = ta[0];                 // k = q*8 + 0..7
            short8 a1 = ta[4];                 // k = 32 + q*8 + 0..7
            f32x4 acc[4];
            #pragma unroll
            for (int mt = 0; mt < 4; ++mt) { acc[mt][0]=0.f; acc[mt][1]=0.f; acc[mt][2]=0.f; acc[mt][3]=0.f; }
            #pragma unroll
            for (int mt = 0; mt < 4; ++mt) {
                const short8* tb = (const short8*)(w2p +
                    (size_t)(g * 64 + mt * 16 + m) * 64 + q * 8);
                short8 b0 = tb[0], b1 = tb[4];
                acc[mt] = __builtin_amdgcn_mfma_f32_16x16x32_bf16(a0, b0, acc[mt], 0, 0, 0);
                acc[mt] = __builtin_amdgcn_mfma_f32_16x16x32_bf16(a1, b1, acc[mt], 0, 0, 0);
            }
            #pragma unroll
            for (int mt = 0; mt < 4; ++mt) {
                const int kk = mt * 16 + m;
                if (kk < 52) {
                    float bv = (kk < KK) ? b2[g * KK + kk] : 0.f;
                    f32x4 v = acc[mt];
                    unsigned r0 = (unsigned)f2bf(v[0] + bv) | ((unsigned)f2bf(v[1] + bv) << 16);
                    unsigned r1 = (unsigned)f2bf(v[2] + bv) | ((unsigned)f2bf(v[3] + bv) << 16);
                    const int pxb = pt * 16 + q * 4;
                    *(uint2*)&wgt[(gl * 52 + kk) * 68 + pxb] = make_uint2(r0, r1);
                }
            }
        }
    }
    __syncthreads();

    // ---- phase 2: conv, 1-row-deep pipelined loads, uniform row-skip ----
    if (tid < 224) {
        const int gl = tid / 112;
        const int rem = tid - gl * 112;
        const int c2 = rem / 14, pq = rem - c2 * 14;
        const int g = gp * 2 + gl;
        const int cc0 = c2 * 2;
        const unsigned short* wg = &wgt[gl * 52 * 68 + pq * 4];
        const bool eL = (pq > 0), eR = (pq < 13);
        const int offL = eL ? 0 : 4;           // clamped, always in-bounds
        const int offR = eR ? 8 : 4;
        const float* yb0 = y + (size_t)(b * 256 + g * 16 + cc0) * HWSZ + pq * 4 - 4;
        const float* yb1 = yb0 + HWSZ;

        float4 cA0, cA1, cA2, cB0, cB1, cB2;
        float4 nA0, nA1, nA2, nB0, nB1, nB2;
        {
            const int hs = h - 3;
            const int hsc = hs < 0 ? 0 : hs;
            const float* r0 = yb0 + hsc * WW;
            const float* r1 = yb1 + hsc * WW;
            cA0 = *(const float4*)(r0 + offL);
            cA1 = *(const float4*)(r0 + 4);
            cA2 = *(const float4*)(r0 + offR);
            cB0 = *(const float4*)(r1 + offL);
            cB1 = *(const float4*)(r1 + 4);
            cB2 = *(const float4*)(r1 + offR);
        }
        float a00=0.f,a01=0.f,a02=0.f,a03=0.f;
        float a10=0.f,a11=0.f,a12=0.f,a13=0.f;

        #pragma unroll
        for (int di = 0; di < KS; ++di) {
            if (di < 6) {                      // issue next row's loads first
                const int hs = h - 2 + di;
                const int hsc = hs < 0 ? 0 : (hs > HH - 1 ? HH - 1 : hs);
                const float* r0 = yb0 + hsc * WW;
                const float* r1 = yb1 + hsc * WW;
                nA0 = *(const float4*)(r0 + offL);
                nA1 = *(const float4*)(r0 + 4);
                nA2 = *(const float4*)(r0 + offR);
                nB0 = *(const float4*)(r1 + offL);
                nB1 = *(const float4*)(r1 + 4);
                nB2 = *(const float4*)(r1 + offR);
            }
            const int hs = h - 3 + di;
            if ((unsigned)hs < HH) {           // block-uniform branch
                float w0[11], w1v[11];
                w0[1] = eL ? cA0.y : 0.f;  w0[2] = eL ? cA0.z : 0.f;  w0[3] = eL ? cA0.w : 0.f;
                w0[4] = cA1.x; w0[5] = cA1.y; w0[6] = cA1.z; w0[7] = cA1.w;
                w0[8] = eR ? cA2.x : 0.f;  w0[9] = eR ? cA2.y : 0.f;  w0[10] = eR ? cA2.z : 0.f;
                w1v[1] = eL ? cB0.y : 0.f; w1v[2] = eL ? cB0.z : 0.f; w1v[3] = eL ? cB0.w : 0.f;
                w1v[4] = cB1.x; w1v[5] = cB1.y; w1v[6] = cB1.z; w1v[7] = cB1.w;
                w1v[8] = eR ? cB2.x : 0.f; w1v[9] = eR ? cB2.y : 0.f; w1v[10] = eR ? cB2.z : 0.f;
                #pragma unroll
                for (int dj = 0; dj < KS; ++dj) {
                    uint2 wr = *(const uint2*)&wg[(di * KS + dj) * 68];
                    float g0 = bflo(wr.x), g1 = bfhi(wr.x);
                    float g2 = bflo(wr.y), g3 = bfhi(wr.y);
                    a00 += g0 * w0[dj + 1];  a01 += g1 * w0[dj + 2];
                    a02 += g2 * w0[dj + 3];  a03 += g3 * w0[dj + 4];
                    a10 += g0 * w1v[dj + 1]; a11 += g1 * w1v[dj + 2];
                    a12 += g2 * w1v[dj + 3]; a13 += g3 * w1v[dj + 4];
                }
            }
            if (di < 6) {
                cA0 = nA0; cA1 = nA1; cA2 = nA2;
                cB0 = nB0; cB1 = nB1; cB2 = nB2;
            }
        }
        float* o0 = out + (size_t)(b * 256 + g * 16 + cc0) * HWSZ + h * WW + pq * 4;
        *(float4*)o0 = make_float4(a00, a01, a02, a03);
        *(float4*)(o0 + HWSZ) = make_float4(a10, a11, a12, a13);
    }
}

extern "C" void kernel_launch(void* const* d_in, const int* in_sizes, int n_in,
                              void* d_out, int out_size, void* d_ws, size_t ws_size,
                              hipStream_t stream) {
    const float* x     = (const float*)d_in[0];
    const float* y     = (const float*)d_in[1];
    const float* w1    = (const float*)d_in[2];
    const float* gamma = (const float*)d_in[3];
    const float* beta  = (const float*)d_in[4];
    const float* mean  = (const float*)d_in[5];
    const float* var   = (const float*)d_in[6];
    const float* w2    = (const float*)d_in[7];
    const float* b2    = (const float*)d_in[8];
    float* out = (float*)d_out;

    unsigned short* t_bf = (unsigned short*)d_ws;          // [12608][64] bf16
    unsigned short* w2p  = t_bf + (size_t)12608 * 64;      // [16*64][64] bf16

    ka_mfma<<<393, 256, 0, stream>>>(x, w1, gamma, beta, mean, var, w2, t_bf, w2p);
    kb_fused<<<1792, 256, 0, stream>>>(y, b2, t_bf, w2p, out);
}

// Round 6
// 43.093 us; speedup vs baseline: 4.2399x; 2.5118x over previous
//
#include <hip/hip_runtime.h>

#define HH 56
#define WW 56
#define HWSZ 3136
#define KS 7
#define KK 49

typedef __attribute__((ext_vector_type(8))) short short8;
typedef __attribute__((ext_vector_type(4))) float f32x4;

__device__ inline unsigned short f2bf(float f) {
    unsigned u = __builtin_bit_cast(unsigned, f);
    u += 0x7FFF + ((u >> 16) & 1);          // RNE
    return (unsigned short)(u >> 16);
}
__device__ inline float bflo(unsigned u) { return __builtin_bit_cast(float, u << 16); }
__device__ inline float bfhi(unsigned u) { return __builtin_bit_cast(float, u & 0xFFFF0000u); }

// --------- Kernel A (MFMA): t[p][64] = relu(BN(x @ w1^T)) in bf16 ---------
// grid 408: blocks 0..391 = 32-pixel tiles; blocks 392..407 = w2->bf16 prep (1 group each).
#define XSTR 260   // shorts per c-block row: 32px*8c + 4 pad
__global__ __launch_bounds__(256) void ka_mfma(
    const float* __restrict__ x, const float* __restrict__ w1,
    const float* __restrict__ gamma, const float* __restrict__ beta,
    const float* __restrict__ mean, const float* __restrict__ var,
    const float* __restrict__ w2,
    unsigned short* __restrict__ t_bf, unsigned short* __restrict__ w2p)
{
    const int tid = threadIdx.x;
    if (blockIdx.x >= 392) {
        // one group per block: 16 independent iterations, hidden under x-tile blocks
        const int g = blockIdx.x - 392;
        #pragma unroll
        for (int it = 0; it < 16; ++it) {
            const int i = it * 256 + tid;
            const int r = i >> 6, k = i & 63;
            float v = (r < KK) ? w2[(g * KK + r) * 64 + k] : 0.f;
            w2p[(size_t)(g * 64 + r) * 64 + k] = f2bf(v);
        }
        return;
    }

    __shared__ __align__(16) unsigned short xls[32 * XSTR];   // ~16.6 KB

    const int p0 = blockIdx.x * 32;
    const int b = p0 / HWSZ, hw0 = p0 - b * HWSZ;

    // ---- stage x tile: [c][p] -> bf16 LDS [cblk][32p][8c] ----
    {
        const int pl = tid & 31, cb0 = tid >> 5;   // cb0 0..7
        const float* xb = x + (size_t)b * 256 * HWSZ + hw0 + pl;
        #pragma unroll
        for (int ps = 0; ps < 4; ++ps) {
            const int cb = ps * 8 + cb0;
            const int c0 = cb * 8;
            unsigned u[4];
            #pragma unroll
            for (int j = 0; j < 4; ++j) {
                float va = xb[(size_t)(c0 + 2 * j) * HWSZ];
                float vb = xb[(size_t)(c0 + 2 * j + 1) * HWSZ];
                u[j] = (unsigned)f2bf(va) | ((unsigned)f2bf(vb) << 16);
            }
            *(uint4*)&xls[cb * XSTR + pl * 8] = make_uint4(u[0], u[1], u[2], u[3]);
        }
    }

    const int lane = tid & 63, wv = tid >> 6;
    const int m = lane & 15, q = lane >> 4;

    // ---- A-fragments straight from global w1 (L2-hot): o=wv*16+m, c=ks*32+q*8+j ----
    short8 af[8];
    {
        const float* wrow = w1 + (wv * 16 + m) * 256 + q * 8;
        #pragma unroll
        for (int ks = 0; ks < 8; ++ks) {
            float4 f0 = *(const float4*)(wrow + ks * 32);
            float4 f1 = *(const float4*)(wrow + ks * 32 + 4);
            short8 s;
            s[0] = (short)f2bf(f0.x); s[1] = (short)f2bf(f0.y);
            s[2] = (short)f2bf(f0.z); s[3] = (short)f2bf(f0.w);
            s[4] = (short)f2bf(f1.x); s[5] = (short)f2bf(f1.y);
            s[6] = (short)f2bf(f1.z); s[7] = (short)f2bf(f1.w);
            af[ks] = s;
        }
    }
    __syncthreads();

    // ---- MFMA: D[o][p], 2 pixel-subtiles ----
    #pragma unroll
    for (int nt = 0; nt < 2; ++nt) {
        f32x4 acc = {0.f, 0.f, 0.f, 0.f};
        #pragma unroll
        for (int ks = 0; ks < 8; ++ks) {
            short8 bfr = *(const short8*)&xls[(ks * 4 + q) * XSTR + (nt * 16 + m) * 8];
            acc = __builtin_amdgcn_mfma_f32_16x16x32_bf16(af[ks], bfr, acc, 0, 0, 0);
        }
        // D: col(lane&15)=p, row((lane>>4)*4+j)=o
        const int ob = wv * 16 + q * 4;
        float4 g4 = *(const float4*)&gamma[ob];
        float4 v4 = *(const float4*)&var[ob];
        float4 m4 = *(const float4*)&mean[ob];
        float4 b4 = *(const float4*)&beta[ob];
        float gg[4] = {g4.x, g4.y, g4.z, g4.w};
        float vv[4] = {v4.x, v4.y, v4.z, v4.w};
        float mm[4] = {m4.x, m4.y, m4.z, m4.w};
        float bb[4] = {b4.x, b4.y, b4.z, b4.w};
        unsigned r0 = 0, r1 = 0;
        #pragma unroll
        for (int j = 0; j < 4; ++j) {
            float sc = gg[j] * rsqrtf(vv[j] + 1e-5f);
            float sh = bb[j] - mm[j] * sc;
            float val = acc[j] * sc + sh;
            val = val > 0.f ? val : 0.f;
            unsigned hb = f2bf(val);
            if (j < 2) r0 |= hb << (16 * j);
            else       r1 |= hb << (16 * (j - 2));
        }
        const int p = p0 + nt * 16 + m;
        *(uint2*)&t_bf[(size_t)p * 64 + ob] = make_uint2(r0, r1);
    }
}

// --------- Kernel B: MFMA weight-GEMM (2 groups) + pipelined dynamic conv ---------
// grid 1792 = 8 group-pairs x 224 (b,h); block 256 (4 waves)
__global__ __launch_bounds__(256) void kb_fused(
    const float* __restrict__ y, const float* __restrict__ b2,
    const unsigned short* __restrict__ t_bf, const unsigned short* __restrict__ w2p,
    float* __restrict__ out)
{
    // wgt bf16 [2 groups][52 kk][68 px-stride]
    __shared__ __align__(16) unsigned short wgt[2 * 52 * 68];

    const int tid = threadIdx.x;
    const int gp = blockIdx.x & 7;             // XCD swizzle
    const int bh = blockIdx.x >> 3;            // 0..223
    const int b = bh / HH, h = bh - b * HH;

    // ---- phase 1: MFMA  wgt[g][kk][px] = sum_k t[px][k] * w2p[g][kk][k] + b2 ----
    {
        const int lane = tid & 63, wv = tid >> 6;
        const int m = lane & 15, q = lane >> 4;
        #pragma unroll
        for (int it = 0; it < 2; ++it) {
            const int tsk = wv + 4 * it;       // 0..7 = 2 groups x 4 pixel-tiles
            const int gl = tsk >> 2, pt = tsk & 3;
            const int g = gp * 2 + gl;
            const int prow = b * HWSZ + h * WW + pt * 16 + m;
            const short8* ta = (const short8*)(t_bf + (size_t)prow * 64 + q * 8);
            short8 a0 = ta[0];                 // k = q*8 + 0..7
            short8 a1 = ta[4];                 // k = 32 + q*8 + 0..7
            f32x4 acc[4];
            #pragma unroll
            for (int mt = 0; mt < 4; ++mt) { acc[mt][0]=0.f; acc[mt][1]=0.f; acc[mt][2]=0.f; acc[mt][3]=0.f; }
            #pragma unroll
            for (int mt = 0; mt < 4; ++mt) {
                const short8* tb = (const short8*)(w2p +
                    (size_t)(g * 64 + mt * 16 + m) * 64 + q * 8);
                short8 b0 = tb[0], b1 = tb[4];
                acc[mt] = __builtin_amdgcn_mfma_f32_16x16x32_bf16(a0, b0, acc[mt], 0, 0, 0);
                acc[mt] = __builtin_amdgcn_mfma_f32_16x16x32_bf16(a1, b1, acc[mt], 0, 0, 0);
            }
            #pragma unroll
            for (int mt = 0; mt < 4; ++mt) {
                const int kk = mt * 16 + m;
                if (kk < 52) {
                    float bv = (kk < KK) ? b2[g * KK + kk] : 0.f;
                    f32x4 v = acc[mt];
                    unsigned r0 = (unsigned)f2bf(v[0] + bv) | ((unsigned)f2bf(v[1] + bv) << 16);
                    unsigned r1 = (unsigned)f2bf(v[2] + bv) | ((unsigned)f2bf(v[3] + bv) << 16);
                    const int pxb = pt * 16 + q * 4;
                    *(uint2*)&wgt[(gl * 52 + kk) * 68 + pxb] = make_uint2(r0, r1);
                }
            }
        }
    }
    __syncthreads();

    // ---- phase 2: conv, 1-row-deep pipelined loads, uniform row-skip ----
    if (tid < 224) {
        const int gl = tid / 112;
        const int rem = tid - gl * 112;
        const int c2 = rem / 14, pq = rem - c2 * 14;
        const int g = gp * 2 + gl;
        const int cc0 = c2 * 2;
        const unsigned short* wg = &wgt[gl * 52 * 68 + pq * 4];
        const bool eL = (pq > 0), eR = (pq < 13);
        const int offL = eL ? 0 : 4;           // clamped, always in-bounds
        const int offR = eR ? 8 : 4;
        const float* yb0 = y + (size_t)(b * 256 + g * 16 + cc0) * HWSZ + pq * 4 - 4;
        const float* yb1 = yb0 + HWSZ;

        float4 cA0, cA1, cA2, cB0, cB1, cB2;
        float4 nA0, nA1, nA2, nB0, nB1, nB2;
        {
            const int hs = h - 3;
            const int hsc = hs < 0 ? 0 : hs;
            const float* r0 = yb0 + hsc * WW;
            const float* r1 = yb1 + hsc * WW;
            cA0 = *(const float4*)(r0 + offL);
            cA1 = *(const float4*)(r0 + 4);
            cA2 = *(const float4*)(r0 + offR);
            cB0 = *(const float4*)(r1 + offL);
            cB1 = *(const float4*)(r1 + 4);
            cB2 = *(const float4*)(r1 + offR);
        }
        float a00=0.f,a01=0.f,a02=0.f,a03=0.f;
        float a10=0.f,a11=0.f,a12=0.f,a13=0.f;

        #pragma unroll
        for (int di = 0; di < KS; ++di) {
            if (di < 6) {                      // issue next row's loads first
                const int hs = h - 2 + di;
                const int hsc = hs < 0 ? 0 : (hs > HH - 1 ? HH - 1 : hs);
                const float* r0 = yb0 + hsc * WW;
                const float* r1 = yb1 + hsc * WW;
                nA0 = *(const float4*)(r0 + offL);
                nA1 = *(const float4*)(r0 + 4);
                nA2 = *(const float4*)(r0 + offR);
                nB0 = *(const float4*)(r1 + offL);
                nB1 = *(const float4*)(r1 + 4);
                nB2 = *(const float4*)(r1 + offR);
            }
            const int hs = h - 3 + di;
            if ((unsigned)hs < HH) {           // block-uniform branch
                float w0[11], w1v[11];
                w0[1] = eL ? cA0.y : 0.f;  w0[2] = eL ? cA0.z : 0.f;  w0[3] = eL ? cA0.w : 0.f;
                w0[4] = cA1.x; w0[5] = cA1.y; w0[6] = cA1.z; w0[7] = cA1.w;
                w0[8] = eR ? cA2.x : 0.f;  w0[9] = eR ? cA2.y : 0.f;  w0[10] = eR ? cA2.z : 0.f;
                w1v[1] = eL ? cB0.y : 0.f; w1v[2] = eL ? cB0.z : 0.f; w1v[3] = eL ? cB0.w : 0.f;
                w1v[4] = cB1.x; w1v[5] = cB1.y; w1v[6] = cB1.z; w1v[7] = cB1.w;
                w1v[8] = eR ? cB2.x : 0.f; w1v[9] = eR ? cB2.y : 0.f; w1v[10] = eR ? cB2.z : 0.f;
                #pragma unroll
                for (int dj = 0; dj < KS; ++dj) {
                    uint2 wr = *(const uint2*)&wg[(di * KS + dj) * 68];
                    float g0 = bflo(wr.x), g1 = bfhi(wr.x);
                    float g2 = bflo(wr.y), g3 = bfhi(wr.y);
                    a00 += g0 * w0[dj + 1];  a01 += g1 * w0[dj + 2];
                    a02 += g2 * w0[dj + 3];  a03 += g3 * w0[dj + 4];
                    a10 += g0 * w1v[dj + 1]; a11 += g1 * w1v[dj + 2];
                    a12 += g2 * w1v[dj + 3]; a13 += g3 * w1v[dj + 4];
                }
            }
            if (di < 6) {
                cA0 = nA0; cA1 = nA1; cA2 = nA2;
                cB0 = nB0; cB1 = nB1; cB2 = nB2;
            }
        }
        float* o0 = out + (size_t)(b * 256 + g * 16 + cc0) * HWSZ + h * WW + pq * 4;
        *(float4*)o0 = make_float4(a00, a01, a02, a03);
        *(float4*)(o0 + HWSZ) = make_float4(a10, a11, a12, a13);
    }
}

extern "C" void kernel_launch(void* const* d_in, const int* in_sizes, int n_in,
                              void* d_out, int out_size, void* d_ws, size_t ws_size,
                              hipStream_t stream) {
    const float* x     = (const float*)d_in[0];
    const float* y     = (const float*)d_in[1];
    const float* w1    = (const float*)d_in[2];
    const float* gamma = (const float*)d_in[3];
    const float* beta  = (const float*)d_in[4];
    const float* mean  = (const float*)d_in[5];
    const float* var   = (const float*)d_in[6];
    const float* w2    = (const float*)d_in[7];
    const float* b2    = (const float*)d_in[8];
    float* out = (float*)d_out;

    unsigned short* t_bf = (unsigned short*)d_ws;          // [12608][64] bf16
    unsigned short* w2p  = t_bf + (size_t)12608 * 64;      // [16*64][64] bf16

    ka_mfma<<<408, 256, 0, stream>>>(x, w1, gamma, beta, mean, var, w2, t_bf, w2p);
    kb_fused<<<1792, 256, 0, stream>>>(y, b2, t_bf, w2p, out);
}